// Round 4
// baseline (2451.133 us; speedup 1.0000x reference)
//
#include <hip/hip_runtime.h>
#include <hip/hip_bf16.h>
#include <cstdint>

#define N_FEATS_IN 256
#define HID 128
#define OUTF 64
#define NBMAX 400   // max buckets (N<=102400); N=100000 -> NB=391

typedef __bf16 bf16x8 __attribute__((ext_vector_type(8)));
typedef __bf16 bf16x4 __attribute__((ext_vector_type(4)));
typedef float f32x4 __attribute__((ext_vector_type(4)));

// Feature tensors between layers are stored XCD-SLICED:
//   F_sl[slice][row][f]  with slice = feat/16, f = feat%16   (bf16)
// Aggregation blocks with (blockIdx & 7) == slice keep a 3.2 MB working set
// resident in their XCD's private L2 (validated R2: feature fetch = table
// size once per XCD). R3 lesson: node processing order must stay sequential
// (bucket-local) or the L2 contract breaks -> no global reordering.
// Aggregation is EDGE-PARALLEL into LDS f32 accumulators (one block per
// (slice,bucket)): constant work per edge, no degree divergence, no CSR.

// Edge encoding after bucketing: pk = ((target & 255) << 24) | src
// (src < 2^24 since N <= 102400). Scatter order within bucket is random
// -> LDS atomic same-address collisions are rare.

// ---- bucketing: LDS counting-sort by 256-node target bucket -------------

__global__ __launch_bounds__(256) void bucket_count(const int* __restrict__ ei, int E,
    int CH, int NB, int* __restrict__ gbk, int* __restrict__ bbase) {
  __shared__ int cnt[NBMAX];
  const int t = threadIdx.x, blk = blockIdx.x;
  for (int i = t; i < NB; i += 256) cnt[i] = 0;
  __syncthreads();
  int base = blk * CH, lim = min(base + CH, E);
  for (int i = base + t; i < lim; i += 256) atomicAdd(&cnt[ei[E + i] >> 8], 1);
  __syncthreads();
  for (int i = t; i < NB; i += 256) {
    int b = (i + blk) % NB;  // stagger to spread atomic line contention
    int v = cnt[b];
    bbase[(size_t)blk * NB + b] = (v > 0) ? atomicAdd(&gbk[b], v) : 0;
  }
}

__global__ __launch_bounds__(512) void bucket_scan(const int* __restrict__ gbk,
    int* __restrict__ gbkoff, int NB, int E) {
  __shared__ int ts[512];
  const int t = threadIdx.x;
  int v = (t < NB) ? gbk[t] : 0;
  ts[t] = v;
  __syncthreads();
  for (int off = 1; off < 512; off <<= 1) {
    int u = (t >= off) ? ts[t - off] : 0;
    __syncthreads();
    ts[t] += u;
    __syncthreads();
  }
  if (t < NB) gbkoff[t] = ts[t] - v;
  if (t == 0) gbkoff[NB] = E;
}

// scatter edges into bucket-grouped packed array via LDS cursors
__global__ __launch_bounds__(256) void bucket_scatter(const int* __restrict__ ei, int E,
    int CH, int NB, const int* __restrict__ gbkoff, const int* __restrict__ bbase,
    unsigned int* __restrict__ pk) {
  __shared__ int cur[NBMAX];
  const int t = threadIdx.x, blk = blockIdx.x;
  for (int i = t; i < NB; i += 256)
    cur[i] = gbkoff[i] + bbase[(size_t)blk * NB + i];
  __syncthreads();
  int base = blk * CH, lim = min(base + CH, E);
  for (int i = base + t; i < lim; i += 256) {
    unsigned int s = (unsigned int)ei[i];
    int c = ei[E + i];
    int p = atomicAdd(&cur[c >> 8], 1);
    pk[p] = ((unsigned int)(c & 255) << 24) | s;
  }
}

// per-bucket degree histogram -> dinv (no CSR needed for edge-parallel agg)
__global__ __launch_bounds__(256) void deg_dinv(const unsigned int* __restrict__ pk,
    const int* __restrict__ gbkoff, int N, float* __restrict__ dinv) {
  __shared__ int cnt[256];
  const int b = blockIdx.x, t = threadIdx.x;
  const int beg = gbkoff[b], end = gbkoff[b + 1];
  cnt[t] = 0;
  __syncthreads();
  for (int i = beg + t; i < end; i += 256) atomicAdd(&cnt[pk[i] >> 24], 1);
  __syncthreads();
  const int node = b * 256 + t;
  if (node < N) dinv[node] = rsqrtf((float)(cnt[t] + 1));  // +1 self-loop
}

// ---- weight repack into MFMA B-fragment order ---------------------------

__global__ __launch_bounds__(256) void pack_all_kernel(const float* __restrict__ W1,
    const float* __restrict__ Wmu, const float* __restrict__ Wlv,
    __bf16* __restrict__ W1p, __bf16* __restrict__ Wcp) {
  int idx = blockIdx.x * 256 + threadIdx.x;  // 32768 + 16384 = 49152
  if (idx < 32768) {
    int j = idx & 7, l = (idx >> 3) & 63, t = (idx >> 9) & 7, s = idx >> 12;
    int k = s * 32 + (l >> 4) * 8 + j;
    int n = t * 16 + (l & 15);
    W1p[idx] = (__bf16)W1[k * HID + n];
  } else if (idx < 49152) {
    int i2 = idx - 32768;
    int j = i2 & 7, l = (i2 >> 3) & 63, t = (i2 >> 9) & 7, s = i2 >> 12;
    int k = s * 32 + (l >> 4) * 8 + j;
    int g = t * 16 + (l & 15);
    float v = (g < OUTF) ? Wmu[k * OUTF + g] : Wlv[k * OUTF + (g - OUTF)];
    Wcp[i2] = (__bf16)v;
  }
}

// ---- GEMM1 (MFMA, no LDS): Yb_sl = slice( dinv[row] * (X @ W1) ) --------

__global__ __launch_bounds__(256) void gemm1_mfma(const float* __restrict__ X,
    const __bf16* __restrict__ Wp, const float* __restrict__ dinv,
    __bf16* __restrict__ Yb, int nrows) {
  const int tid = threadIdx.x;
  const int lane = tid & 63;
  const int wave = tid >> 6;
  const int lm = lane & 15;
  const int q = lane >> 4;
  const int rowbase = blockIdx.x * 128 + wave * 32;

  const int r0 = min(rowbase + lm, nrows - 1);
  const int r1 = min(rowbase + 16 + lm, nrows - 1);
  const float* x0 = X + (size_t)r0 * N_FEATS_IN + q * 8;
  const float* x1 = X + (size_t)r1 * N_FEATS_IN + q * 8;

  const bf16x8* wp = (const bf16x8*)Wp;

  f32x4 acc[2][8];
#pragma unroll
  for (int m = 0; m < 2; ++m)
#pragma unroll
    for (int t = 0; t < 8; ++t) acc[m][t] = (f32x4)0.f;

#pragma unroll
  for (int s = 0; s < 8; ++s) {
    float4 l0 = *(const float4*)(x0 + s * 32);
    float4 h0 = *(const float4*)(x0 + s * 32 + 4);
    float4 l1 = *(const float4*)(x1 + s * 32);
    float4 h1 = *(const float4*)(x1 + s * 32 + 4);
    bf16x8 a0, a1;
    a0[0] = (__bf16)l0.x; a0[1] = (__bf16)l0.y; a0[2] = (__bf16)l0.z; a0[3] = (__bf16)l0.w;
    a0[4] = (__bf16)h0.x; a0[5] = (__bf16)h0.y; a0[6] = (__bf16)h0.z; a0[7] = (__bf16)h0.w;
    a1[0] = (__bf16)l1.x; a1[1] = (__bf16)l1.y; a1[2] = (__bf16)l1.z; a1[3] = (__bf16)l1.w;
    a1[4] = (__bf16)h1.x; a1[5] = (__bf16)h1.y; a1[6] = (__bf16)h1.z; a1[7] = (__bf16)h1.w;
#pragma unroll
    for (int t = 0; t < 8; ++t) {
      bf16x8 b = wp[(s * 8 + t) * 64 + lane];
      acc[0][t] = __builtin_amdgcn_mfma_f32_16x16x32_bf16(a0, b, acc[0][t], 0, 0, 0);
      acc[1][t] = __builtin_amdgcn_mfma_f32_16x16x32_bf16(a1, b, acc[1][t], 0, 0, 0);
    }
  }

  float dd[2][4];
#pragma unroll
  for (int m = 0; m < 2; ++m)
#pragma unroll
    for (int r2 = 0; r2 < 4; ++r2) {
      int row = rowbase + m * 16 + q * 4 + r2;
      dd[m][r2] = (row < nrows) ? dinv[row] : 0.f;
    }

  // sliced store: slice = t (16 cols per t-tile), col-in-slice = lm
#pragma unroll
  for (int m = 0; m < 2; ++m) {
    int rb = rowbase + m * 16 + q * 4;
#pragma unroll
    for (int t = 0; t < 8; ++t) {
      __bf16* yslice = Yb + (size_t)t * nrows * 16;
#pragma unroll
      for (int r2 = 0; r2 < 4; ++r2) {
        int row = rb + r2;
        if (row < nrows)
          yslice[(size_t)row * 16 + lm] = (__bf16)(acc[m][t][r2] * dd[m][r2]);
      }
    }
  }
}

// ---- aggregation: edge-parallel, LDS f32 accumulators, XCD-sliced -------
// Block = (slice s = blockIdx&7, bucket b = blockIdx>>3). LDS holds f32
// accumulators for the bucket's 256 nodes x 16 feats (stride 17 to spread
// banks). Init with the self term F'[c]; stream the bucket's packed edges
// (constant work per edge -> no divergence); epilogue applies dinv/bias.
//   relu: out = d*relu(d*sum + b)     plain: out = d*sum

__global__ __launch_bounds__(256) void agg_kernel(const __bf16* __restrict__ Fin,
    const unsigned int* __restrict__ pk, const int* __restrict__ gbkoff,
    const float* __restrict__ dinv, const float* __restrict__ bias,
    __bf16* __restrict__ Fout, int do_relu, int N) {
  __shared__ float acc[256 * 17];  // 17 KB, stride-17 pad (17 odd -> 2-way banks)
  const int tid = threadIdx.x;
  const int s = blockIdx.x & 7;
  const int b = blockIdx.x >> 3;
  const __bf16* F = Fin + (size_t)s * N * 16;
  const int gn = b * 256 + tid;

  // init accumulators with self term
  if (gn < N) {
    const bf16x8* fr = (const bf16x8*)(F + (size_t)gn * 16);
    bf16x8 r0 = fr[0], r1 = fr[1];
#pragma unroll
    for (int k = 0; k < 8; ++k) acc[tid * 17 + k] = (float)r0[k];
#pragma unroll
    for (int k = 0; k < 8; ++k) acc[tid * 17 + 8 + k] = (float)r1[k];
  }
  __syncthreads();

  const int beg = gbkoff[b], end = gbkoff[b + 1];
  const int g = tid >> 2;   // edge group (0..63)
  const int fl = tid & 3;   // 4 feats per lane
  int e = beg + g;
  // 2-way unroll: two independent gather chains in flight per lane
  for (; e + 64 < end; e += 128) {
    unsigned int p0 = pk[e], p1 = pk[e + 64];
    bf16x4 v0 = ((const bf16x4*)(F + (size_t)(p0 & 0xFFFFFFu) * 16))[fl];
    bf16x4 v1 = ((const bf16x4*)(F + (size_t)(p1 & 0xFFFFFFu) * 16))[fl];
    int t0 = (int)(p0 >> 24) * 17 + fl * 4;
    int t1 = (int)(p1 >> 24) * 17 + fl * 4;
#pragma unroll
    for (int k = 0; k < 4; ++k) atomicAdd(&acc[t0 + k], (float)v0[k]);
#pragma unroll
    for (int k = 0; k < 4; ++k) atomicAdd(&acc[t1 + k], (float)v1[k]);
  }
  for (; e < end; e += 64) {
    unsigned int p0 = pk[e];
    bf16x4 v0 = ((const bf16x4*)(F + (size_t)(p0 & 0xFFFFFFu) * 16))[fl];
    int t0 = (int)(p0 >> 24) * 17 + fl * 4;
#pragma unroll
    for (int k = 0; k < 4; ++k) atomicAdd(&acc[t0 + k], (float)v0[k]);
  }
  __syncthreads();

  // epilogue: scale + bias + relu, store bf16 (coalesced 32 B per thread)
  if (gn < N) {
    const float d = dinv[gn];
    bf16x8 o0, o1;
    if (do_relu) {
#pragma unroll
      for (int k = 0; k < 8; ++k)
        o0[k] = (__bf16)(fmaxf(fmaf(d, acc[tid * 17 + k], bias[s * 16 + k]), 0.f) * d);
#pragma unroll
      for (int k = 0; k < 8; ++k)
        o1[k] = (__bf16)(fmaxf(fmaf(d, acc[tid * 17 + 8 + k], bias[s * 16 + 8 + k]), 0.f) * d);
    } else {
#pragma unroll
      for (int k = 0; k < 8; ++k) o0[k] = (__bf16)(d * acc[tid * 17 + k]);
#pragma unroll
      for (int k = 0; k < 8; ++k) o1[k] = (__bf16)(d * acc[tid * 17 + 8 + k]);
    }
    bf16x8* op = (bf16x8*)(Fout + (size_t)s * N * 16 + (size_t)gn * 16);
    op[0] = o0;
    op[1] = o1;
  }
}

// ---- GEMM2 (MFMA): [mu|lv] = G[N][128] @ Wc[128][128] + bias ------------
// A rows gathered from sliced layout: 16B chunk k lives at slice k>>1,
// offset (k&1)*8.

__global__ __launch_bounds__(256) void gemm2_mfma(const __bf16* __restrict__ Gb,
    const __bf16* __restrict__ Wp, const float* __restrict__ bmu,
    const float* __restrict__ blv, float* __restrict__ out, int nrows, int ntiles) {
  __shared__ __bf16 bs[16384];  // 32 KB: full Wc in B-frag order
  const int tid = threadIdx.x;
  {
    const float4* s4 = (const float4*)Wp;
    float4* d4 = (float4*)bs;
#pragma unroll
    for (int i = 0; i < 8; ++i) d4[tid + 256 * i] = s4[tid + 256 * i];
  }
  __syncthreads();
  const int lane = tid & 63;
  const int wave = tid >> 6;
  const int lm = lane & 15;
  const int q = lane >> 4;
  const bf16x8* bsv = (const bf16x8*)bs;

  float bv[8];
  size_t obase[8];
#pragma unroll
  for (int t = 0; t < 8; ++t) {
    int col = t * 16 + lm;
    bv[t] = (col < OUTF) ? bmu[col] : blv[col - OUTF];
    obase[t] = (col < OUTF) ? (size_t)col : ((size_t)nrows * OUTF + (col - OUTF));
  }

  for (int tile = blockIdx.x; tile < ntiles; tile += gridDim.x) {
    const int row0 = tile * 64 + wave * 16;
    const int r = min(row0 + lm, nrows - 1);

    bf16x8 xa[4];
#pragma unroll
    for (int si = 0; si < 4; ++si) {
      int chunk = si * 4 + q;  // feats [8*chunk, 8*chunk+8)
      xa[si] = *(const bf16x8*)(Gb + (size_t)(chunk >> 1) * nrows * 16 +
                                (size_t)r * 16 + (chunk & 1) * 8);
    }

    f32x4 acc[8];
#pragma unroll
    for (int t = 0; t < 8; ++t) acc[t] = (f32x4)0.f;

#pragma unroll
    for (int si = 0; si < 4; ++si) {
#pragma unroll
      for (int t = 0; t < 8; ++t)
        acc[t] = __builtin_amdgcn_mfma_f32_16x16x32_bf16(xa[si], bsv[(si * 8 + t) * 64 + lane],
                                                         acc[t], 0, 0, 0);
    }
#pragma unroll
    for (int t = 0; t < 8; ++t) {
#pragma unroll
      for (int r2 = 0; r2 < 4; ++r2) {
        int row = row0 + q * 4 + r2;
        if (row < nrows) out[obase[t] + (size_t)row * OUTF] = acc[t][r2] + bv[t];
      }
    }
  }
}

// ---- launch -------------------------------------------------------------

extern "C" void kernel_launch(void* const* d_in, const int* in_sizes, int n_in,
                              void* d_out, int out_size, void* d_ws, size_t ws_size,
                              hipStream_t stream) {
  const float* X   = (const float*)d_in[0];
  const int*   ei  = (const int*)d_in[1];
  const float* W1  = (const float*)d_in[2];
  const float* b1  = (const float*)d_in[3];
  const float* Wmu = (const float*)d_in[4];
  const float* bmu = (const float*)d_in[5];
  const float* Wlv = (const float*)d_in[6];
  const float* blv = (const float*)d_in[7];
  float* out = (float*)d_out;

  const int N = in_sizes[0] / N_FEATS_IN;   // 100000
  const int E = in_sizes[1] / 2;            // 1600000

  char* ws = (char*)d_ws;
  size_t off = 0;
  auto alloc = [&](size_t bytes) -> void* {
    void* p = ws + off;
    off += (bytes + 255) & ~(size_t)255;
    return p;
  };
  __bf16* Yb   = (__bf16*)alloc((size_t)N * HID * 2);  // gemm1 out (sliced); reused as G
  __bf16* Hb   = (__bf16*)alloc((size_t)N * HID * 2);  // dinv*relu(Â Y + b1) (sliced)
  float* dinv  = (float*)alloc((size_t)N * 4);
  unsigned int* pk = (unsigned int*)alloc((size_t)E * 4);  // packed (tloc<<24)|src
  int*   gbk   = (int*)alloc((size_t)NBMAX * 4);
  int*   gbkoff = (int*)alloc((size_t)(NBMAX + 1) * 4);
  int*   bbase = (int*)alloc((size_t)256 * NBMAX * 4);
  __bf16* W1p  = (__bf16*)alloc(32768 * 2);
  __bf16* Wcp  = (__bf16*)alloc(16384 * 2);
  (void)ws_size; (void)n_in; (void)out_size;

  const int NB = (N + 255) >> 8;            // 391
  const int P = 256;
  const int CH = (E + P - 1) / P;           // 6250

  hipMemsetAsync(gbk, 0, (size_t)NB * 4, stream);
  bucket_count<<<P, 256, 0, stream>>>(ei, E, CH, NB, gbk, bbase);
  bucket_scan<<<1, 512, 0, stream>>>(gbk, gbkoff, NB, E);
  bucket_scatter<<<P, 256, 0, stream>>>(ei, E, CH, NB, gbkoff, bbase, pk);
  deg_dinv<<<NB, 256, 0, stream>>>(pk, gbkoff, N, dinv);
  pack_all_kernel<<<192, 256, 0, stream>>>(W1, Wmu, Wlv, W1p, Wcp);

  int g1 = (N + 127) / 128;
  gemm1_mfma<<<g1, 256, 0, stream>>>(X, W1p, dinv, Yb, N);
  int ga = NB * 8;  // (slice, bucket) blocks; slice = blockIdx&7 -> XCD pin
  agg_kernel<<<ga, 256, 0, stream>>>(Yb, pk, gbkoff, dinv, b1, Hb, 1, N);  // H'
  agg_kernel<<<ga, 256, 0, stream>>>(Hb, pk, gbkoff, dinv, b1, Yb, 0, N);  // G
  int ntiles2 = (N + 63) / 64;
  int g2 = ntiles2 < 768 ? ntiles2 : 768;
  gemm2_mfma<<<g2, 256, 0, stream>>>(Yb, Wcp, bmu, blv, out, N, ntiles2);
}

// Round 5
// 506.890 us; speedup vs baseline: 4.8356x; 4.8356x over previous
//
#include <hip/hip_runtime.h>
#include <hip/hip_bf16.h>
#include <cstdint>

#define N_FEATS_IN 256
#define HID 128
#define OUTF 64
#define NBMAX 400   // max buckets (N<=102400); N=100000 -> NB=391
#define BCAP 6144   // max edges staged in LDS per bucket (mean 4096, 30 sigma margin)

typedef __bf16 bf16x8 __attribute__((ext_vector_type(8)));
typedef __bf16 bf16x4 __attribute__((ext_vector_type(4)));
typedef float f32x4 __attribute__((ext_vector_type(4)));

// Feature tensors between layers are stored XCD-SLICED:
//   F_sl[slice][row][f]  with slice = feat/16, f = feat%16   (bf16)
// Aggregation blocks with (blockIdx & 7) == slice keep a 3.2 MB working set
// resident in their XCD's private L2 (validated R2: feature fetch = table
// size once per XCD, 207->70 MB).
// HARD LESSONS (measured):
//  - R3: GLOBAL node reorder breaks the sequential-window L2 contract
//    (FETCH 70->327 MB). Reordering must stay bucket-local.
//  - R4: f32 LDS atomicAdd lowers to a CAS retry loop on gfx950 ->
//    12.5x regression (1098us, VALUBusy 1.7%). Never in a hot loop.
// This version: R2's node-parallel gather agg + BUCKET-LOCAL degree sort
// (nperm) so each wave's 16 nodes have near-identical degree -> uniform
// edge-loop trip counts without losing locality.

// ---- CSR build: LDS counting-sort by 256-node bucket --------------------

__global__ __launch_bounds__(256) void bucket_count(const int* __restrict__ ei, int E,
    int CH, int NB, int* __restrict__ gbk, int* __restrict__ bbase) {
  __shared__ int cnt[NBMAX];
  const int t = threadIdx.x, blk = blockIdx.x;
  for (int i = t; i < NB; i += 256) cnt[i] = 0;
  __syncthreads();
  int base = blk * CH, lim = min(base + CH, E);
  for (int i = base + t; i < lim; i += 256) atomicAdd(&cnt[ei[E + i] >> 8], 1);
  __syncthreads();
  for (int i = t; i < NB; i += 256) {
    int b = (i + blk) % NB;  // stagger to spread atomic line contention
    int v = cnt[b];
    bbase[(size_t)blk * NB + b] = (v > 0) ? atomicAdd(&gbk[b], v) : 0;
  }
}

__global__ __launch_bounds__(512) void bucket_scan(const int* __restrict__ gbk,
    int* __restrict__ gbkoff, int NB, int E) {
  __shared__ int ts[512];
  const int t = threadIdx.x;
  int v = (t < NB) ? gbk[t] : 0;
  ts[t] = v;
  __syncthreads();
  for (int off = 1; off < 512; off <<= 1) {
    int u = (t >= off) ? ts[t - off] : 0;
    __syncthreads();
    ts[t] += u;
    __syncthreads();
  }
  if (t < NB) gbkoff[t] = ts[t] - v;
  if (t == 0) gbkoff[NB] = E;
}

__global__ __launch_bounds__(256) void bucket_scatter(const int* __restrict__ ei, int E,
    int CH, int NB, const int* __restrict__ gbkoff, const int* __restrict__ bbase,
    int2* __restrict__ bucketed) {
  __shared__ int cur[NBMAX];
  const int t = threadIdx.x, blk = blockIdx.x;
  for (int i = t; i < NB; i += 256)
    cur[i] = gbkoff[i] + bbase[(size_t)blk * NB + i];
  __syncthreads();
  int base = blk * CH, lim = min(base + CH, E);
  for (int i = base + t; i < lim; i += 256) {
    int s = ei[i];
    int c = ei[E + i];
    int p = atomicAdd(&cur[c >> 8], 1);
    bucketed[p] = make_int2(s, c);
  }
}

// K4: per-bucket local CSR (ptr, dinv, target-sorted csrc) + BUCKET-LOCAL
// degree sort: nperm[b*256 + rank] = node, rank by 64-bin counting sort of
// the bucket's degrees (all in LDS; valid nodes pack to the front, so
// "slot < N" remains the validity test).
__global__ __launch_bounds__(256) void bucket_csr(const int2* __restrict__ bucketed,
    const int* __restrict__ gbkoff, int NB, int N, int E,
    float* __restrict__ dinv, int* __restrict__ ptr, int* __restrict__ csrc,
    int* __restrict__ nperm) {
  __shared__ int2 eb[BCAP];
  __shared__ int cnt[256], scn[256], cur[256];
  __shared__ int dh[64], dhs[64];
  const int b = blockIdx.x, t = threadIdx.x;
  const int beg = gbkoff[b], end = gbkoff[b + 1];
  const int M = end - beg;
  cnt[t] = 0;
  if (t < 64) dh[t] = 0;
  __syncthreads();
  const bool inlds = (M <= BCAP);
  if (inlds) {
    for (int i = t; i < M; i += 256) {
      int2 r = bucketed[beg + i];
      eb[i] = r;
      atomicAdd(&cnt[r.y & 255], 1);
    }
  } else {
    for (int i = t; i < M; i += 256) atomicAdd(&cnt[bucketed[beg + i].y & 255], 1);
  }
  __syncthreads();
  const int c0 = cnt[t];
  scn[t] = c0;
  __syncthreads();
  for (int off = 1; off < 256; off <<= 1) {
    int u = (t >= off) ? scn[t - off] : 0;
    __syncthreads();
    scn[t] += u;
    __syncthreads();
  }
  const int excl = scn[t] - c0;
  const int node = b * 256 + t;
  int bin = 0, lrk = 0;
  if (node < N) {
    ptr[node] = beg + excl;
    dinv[node] = rsqrtf((float)(c0 + 1));  // +1 self-loop
    bin = min(c0, 63);
    lrk = atomicAdd(&dh[bin], 1);          // LDS int atomic: native ds_add
  }
  if (b == NB - 1 && t == 0) ptr[N] = E;
  cur[t] = excl;
  __syncthreads();
  if (t < 64) {  // wave 0: exclusive scan of the 64 degree bins
    int v = dh[t];
    int x = v;
    for (int off = 1; off < 64; off <<= 1) {
      int u = __shfl_up(x, off);
      if (t >= off) x += u;
    }
    dhs[t] = x - v;
  }
  __syncthreads();
  if (node < N) nperm[b * 256 + dhs[bin] + lrk] = node;
  if (inlds) {
    for (int i = t; i < M; i += 256) {
      int2 r = eb[i];
      int slot = atomicAdd(&cur[r.y & 255], 1);
      csrc[beg + slot] = r.x;
    }
  } else {
    for (int i = t; i < M; i += 256) {
      int2 r = bucketed[beg + i];
      int slot = atomicAdd(&cur[r.y & 255], 1);
      csrc[beg + slot] = r.x;
    }
  }
}

// ---- weight repack into MFMA B-fragment order ---------------------------

__global__ __launch_bounds__(256) void pack_all_kernel(const float* __restrict__ W1,
    const float* __restrict__ Wmu, const float* __restrict__ Wlv,
    __bf16* __restrict__ W1p, __bf16* __restrict__ Wcp) {
  int idx = blockIdx.x * 256 + threadIdx.x;  // 32768 + 16384 = 49152
  if (idx < 32768) {
    int j = idx & 7, l = (idx >> 3) & 63, t = (idx >> 9) & 7, s = idx >> 12;
    int k = s * 32 + (l >> 4) * 8 + j;
    int n = t * 16 + (l & 15);
    W1p[idx] = (__bf16)W1[k * HID + n];
  } else if (idx < 49152) {
    int i2 = idx - 32768;
    int j = i2 & 7, l = (i2 >> 3) & 63, t = (i2 >> 9) & 7, s = i2 >> 12;
    int k = s * 32 + (l >> 4) * 8 + j;
    int g = t * 16 + (l & 15);
    float v = (g < OUTF) ? Wmu[k * OUTF + g] : Wlv[k * OUTF + (g - OUTF)];
    Wcp[i2] = (__bf16)v;
  }
}

// ---- GEMM1 (MFMA, no LDS): Yb_sl = slice( dinv[row] * (X @ W1) ) --------

__global__ __launch_bounds__(256) void gemm1_mfma(const float* __restrict__ X,
    const __bf16* __restrict__ Wp, const float* __restrict__ dinv,
    __bf16* __restrict__ Yb, int nrows) {
  const int tid = threadIdx.x;
  const int lane = tid & 63;
  const int wave = tid >> 6;
  const int lm = lane & 15;
  const int q = lane >> 4;
  const int rowbase = blockIdx.x * 128 + wave * 32;

  const int r0 = min(rowbase + lm, nrows - 1);
  const int r1 = min(rowbase + 16 + lm, nrows - 1);
  const float* x0 = X + (size_t)r0 * N_FEATS_IN + q * 8;
  const float* x1 = X + (size_t)r1 * N_FEATS_IN + q * 8;

  const bf16x8* wp = (const bf16x8*)Wp;

  f32x4 acc[2][8];
#pragma unroll
  for (int m = 0; m < 2; ++m)
#pragma unroll
    for (int t = 0; t < 8; ++t) acc[m][t] = (f32x4)0.f;

#pragma unroll
  for (int s = 0; s < 8; ++s) {
    float4 l0 = *(const float4*)(x0 + s * 32);
    float4 h0 = *(const float4*)(x0 + s * 32 + 4);
    float4 l1 = *(const float4*)(x1 + s * 32);
    float4 h1 = *(const float4*)(x1 + s * 32 + 4);
    bf16x8 a0, a1;
    a0[0] = (__bf16)l0.x; a0[1] = (__bf16)l0.y; a0[2] = (__bf16)l0.z; a0[3] = (__bf16)l0.w;
    a0[4] = (__bf16)h0.x; a0[5] = (__bf16)h0.y; a0[6] = (__bf16)h0.z; a0[7] = (__bf16)h0.w;
    a1[0] = (__bf16)l1.x; a1[1] = (__bf16)l1.y; a1[2] = (__bf16)l1.z; a1[3] = (__bf16)l1.w;
    a1[4] = (__bf16)h1.x; a1[5] = (__bf16)h1.y; a1[6] = (__bf16)h1.z; a1[7] = (__bf16)h1.w;
#pragma unroll
    for (int t = 0; t < 8; ++t) {
      bf16x8 b = wp[(s * 8 + t) * 64 + lane];
      acc[0][t] = __builtin_amdgcn_mfma_f32_16x16x32_bf16(a0, b, acc[0][t], 0, 0, 0);
      acc[1][t] = __builtin_amdgcn_mfma_f32_16x16x32_bf16(a1, b, acc[1][t], 0, 0, 0);
    }
  }

  float dd[2][4];
#pragma unroll
  for (int m = 0; m < 2; ++m)
#pragma unroll
    for (int r2 = 0; r2 < 4; ++r2) {
      int row = rowbase + m * 16 + q * 4 + r2;
      dd[m][r2] = (row < nrows) ? dinv[row] : 0.f;
    }

  // sliced store: slice = t (16 cols per t-tile), col-in-slice = lm
#pragma unroll
  for (int m = 0; m < 2; ++m) {
    int rb = rowbase + m * 16 + q * 4;
#pragma unroll
    for (int t = 0; t < 8; ++t) {
      __bf16* yslice = Yb + (size_t)t * nrows * 16;
#pragma unroll
      for (int r2 = 0; r2 < 4; ++r2) {
        int row = rb + r2;
        if (row < nrows)
          yslice[(size_t)row * 16 + lm] = (__bf16)(acc[m][t][r2] * dd[m][r2]);
      }
    }
  }
}

// ---- aggregation, XCD-sliced + bucket-local degree-sorted ---------------
// slice = blockIdx & 7 (pins slice to one XCD); c = nperm[slot] stays inside
// slot's own 256-node bucket -> L2 window preserved; wave's 16 nodes are
// consecutive in the bucket's degree order -> uniform trip counts.
//   sum = F'[c] + sum_e F'[src_e]
//   relu: out = d*relu(d*sum + b)     plain: out = d*sum

__global__ __launch_bounds__(256) void agg_kernel(const __bf16* __restrict__ Fin,
    const int* __restrict__ ptr, const int* __restrict__ csrc,
    const float* __restrict__ dinv, const float* __restrict__ bias,
    const int* __restrict__ nperm,
    __bf16* __restrict__ Fout, int do_relu, int N) {
  const int tid = threadIdx.x;
  const int s = blockIdx.x & 7;
  const int tb = blockIdx.x >> 3;
  const int g = tid >> 2;    // node slot within block (0..63)
  const int fl = tid & 3;    // 4 feats per lane within the 16-feat slice
  const int idx = tb * 64 + g;
  if (idx >= N) return;
  const int c = nperm[idx];  // same bucket as idx

  const __bf16* F = Fin + (size_t)s * N * 16;
  const float d = dinv[c];
  bf16x4 sv = ((const bf16x4*)(F + (size_t)c * 16))[fl];  // self term
  float a0 = (float)sv[0], a1 = (float)sv[1], a2 = (float)sv[2], a3 = (float)sv[3];

  const int beg = ptr[c], end = ptr[c + 1];
  int e = beg;
  for (; e + 8 <= end; e += 8) {
    int r[8];
#pragma unroll
    for (int i = 0; i < 8; ++i) r[i] = csrc[e + i];
    bf16x4 v[8];
#pragma unroll
    for (int i = 0; i < 8; ++i) v[i] = ((const bf16x4*)(F + (size_t)r[i] * 16))[fl];
#pragma unroll
    for (int i = 0; i < 8; ++i) {
      a0 += (float)v[i][0];
      a1 += (float)v[i][1];
      a2 += (float)v[i][2];
      a3 += (float)v[i][3];
    }
  }
  for (; e < end; ++e) {
    int r = csrc[e];
    bf16x4 v = ((const bf16x4*)(F + (size_t)r * 16))[fl];
    a0 += (float)v[0];
    a1 += (float)v[1];
    a2 += (float)v[2];
    a3 += (float)v[3];
  }

  if (do_relu) {
    float4 bv = ((const float4*)bias)[s * 4 + fl];
    a0 = fmaxf(fmaf(d, a0, bv.x), 0.f) * d;
    a1 = fmaxf(fmaf(d, a1, bv.y), 0.f) * d;
    a2 = fmaxf(fmaf(d, a2, bv.z), 0.f) * d;
    a3 = fmaxf(fmaf(d, a3, bv.w), 0.f) * d;
  } else {
    a0 *= d; a1 *= d; a2 *= d; a3 *= d;
  }
  bf16x4 o;
  o[0] = (__bf16)a0; o[1] = (__bf16)a1; o[2] = (__bf16)a2; o[3] = (__bf16)a3;
  ((bf16x4*)(Fout + (size_t)s * N * 16 + (size_t)c * 16))[fl] = o;
}

// ---- GEMM2 (MFMA): [mu|lv] = G[N][128] @ Wc[128][128] + bias ------------
// A rows gathered from sliced layout: 16B chunk k lives at slice k>>1,
// offset (k&1)*8.

__global__ __launch_bounds__(256) void gemm2_mfma(const __bf16* __restrict__ Gb,
    const __bf16* __restrict__ Wp, const float* __restrict__ bmu,
    const float* __restrict__ blv, float* __restrict__ out, int nrows, int ntiles) {
  __shared__ __bf16 bs[16384];  // 32 KB: full Wc in B-frag order
  const int tid = threadIdx.x;
  {
    const float4* s4 = (const float4*)Wp;
    float4* d4 = (float4*)bs;
#pragma unroll
    for (int i = 0; i < 8; ++i) d4[tid + 256 * i] = s4[tid + 256 * i];
  }
  __syncthreads();
  const int lane = tid & 63;
  const int wave = tid >> 6;
  const int lm = lane & 15;
  const int q = lane >> 4;
  const bf16x8* bsv = (const bf16x8*)bs;

  float bv[8];
  size_t obase[8];
#pragma unroll
  for (int t = 0; t < 8; ++t) {
    int col = t * 16 + lm;
    bv[t] = (col < OUTF) ? bmu[col] : blv[col - OUTF];
    obase[t] = (col < OUTF) ? (size_t)col : ((size_t)nrows * OUTF + (col - OUTF));
  }

  for (int tile = blockIdx.x; tile < ntiles; tile += gridDim.x) {
    const int row0 = tile * 64 + wave * 16;
    const int r = min(row0 + lm, nrows - 1);

    bf16x8 xa[4];
#pragma unroll
    for (int si = 0; si < 4; ++si) {
      int chunk = si * 4 + q;  // feats [8*chunk, 8*chunk+8)
      xa[si] = *(const bf16x8*)(Gb + (size_t)(chunk >> 1) * nrows * 16 +
                                (size_t)r * 16 + (chunk & 1) * 8);
    }

    f32x4 acc[8];
#pragma unroll
    for (int t = 0; t < 8; ++t) acc[t] = (f32x4)0.f;

#pragma unroll
    for (int si = 0; si < 4; ++si) {
#pragma unroll
      for (int t = 0; t < 8; ++t)
        acc[t] = __builtin_amdgcn_mfma_f32_16x16x32_bf16(xa[si], bsv[(si * 8 + t) * 64 + lane],
                                                         acc[t], 0, 0, 0);
    }
#pragma unroll
    for (int t = 0; t < 8; ++t) {
#pragma unroll
      for (int r2 = 0; r2 < 4; ++r2) {
        int row = row0 + q * 4 + r2;
        if (row < nrows) out[obase[t] + (size_t)row * OUTF] = acc[t][r2] + bv[t];
      }
    }
  }
}

// ---- launch -------------------------------------------------------------

extern "C" void kernel_launch(void* const* d_in, const int* in_sizes, int n_in,
                              void* d_out, int out_size, void* d_ws, size_t ws_size,
                              hipStream_t stream) {
  const float* X   = (const float*)d_in[0];
  const int*   ei  = (const int*)d_in[1];
  const float* W1  = (const float*)d_in[2];
  const float* b1  = (const float*)d_in[3];
  const float* Wmu = (const float*)d_in[4];
  const float* bmu = (const float*)d_in[5];
  const float* Wlv = (const float*)d_in[6];
  const float* blv = (const float*)d_in[7];
  float* out = (float*)d_out;

  const int N = in_sizes[0] / N_FEATS_IN;   // 100000
  const int E = in_sizes[1] / 2;            // 1600000

  char* ws = (char*)d_ws;
  size_t off = 0;
  auto alloc = [&](size_t bytes) -> void* {
    void* p = ws + off;
    off += (bytes + 255) & ~(size_t)255;
    return p;
  };
  __bf16* Yb   = (__bf16*)alloc((size_t)N * HID * 2);  // gemm1 out (sliced); reused as G
  __bf16* Hb   = (__bf16*)alloc((size_t)N * HID * 2);  // dinv*relu(Â Y + b1) (sliced)
  float* dinv  = (float*)alloc((size_t)N * 4);
  int*   ptr   = (int*)alloc((size_t)(N + 1) * 4);
  int2*  bucketed = (int2*)alloc((size_t)E * 8);
  int*   csrc  = (int*)alloc((size_t)E * 4);
  int*   nperm = (int*)alloc((size_t)N * 4);
  int*   gbk   = (int*)alloc((size_t)NBMAX * 4);
  int*   gbkoff = (int*)alloc((size_t)(NBMAX + 1) * 4);
  int*   bbase = (int*)alloc((size_t)256 * NBMAX * 4);
  __bf16* W1p  = (__bf16*)alloc(32768 * 2);
  __bf16* Wcp  = (__bf16*)alloc(16384 * 2);
  (void)ws_size; (void)n_in; (void)out_size;

  const int NB = (N + 255) >> 8;            // 391
  const int P = 256;
  const int CH = (E + P - 1) / P;           // 6250

  hipMemsetAsync(gbk, 0, (size_t)NB * 4, stream);
  bucket_count<<<P, 256, 0, stream>>>(ei, E, CH, NB, gbk, bbase);
  bucket_scan<<<1, 512, 0, stream>>>(gbk, gbkoff, NB, E);
  bucket_scatter<<<P, 256, 0, stream>>>(ei, E, CH, NB, gbkoff, bbase, bucketed);
  bucket_csr<<<NB, 256, 0, stream>>>(bucketed, gbkoff, NB, N, E, dinv, ptr, csrc, nperm);
  pack_all_kernel<<<192, 256, 0, stream>>>(W1, Wmu, Wlv, W1p, Wcp);

  int g1 = (N + 127) / 128;
  gemm1_mfma<<<g1, 256, 0, stream>>>(X, W1p, dinv, Yb, N);
  int ga = ((N + 63) / 64) * 8;  // 8 slices x node-slot blocks
  agg_kernel<<<ga, 256, 0, stream>>>(Yb, ptr, csrc, dinv, b1, nperm, Hb, 1, N);  // H'
  agg_kernel<<<ga, 256, 0, stream>>>(Hb, ptr, csrc, dinv, b1, nperm, Yb, 0, N);  // G
  int ntiles2 = (N + 63) / 64;
  int g2 = ntiles2 < 768 ? ntiles2 : 768;
  gemm2_mfma<<<g2, 256, 0, stream>>>(Yb, Wcp, bmu, blv, out, N, ntiles2);
}

// Round 6
// 430.117 us; speedup vs baseline: 5.6988x; 1.1785x over previous
//
#include <hip/hip_runtime.h>
#include <hip/hip_bf16.h>
#include <cstdint>

#define N_FEATS_IN 256
#define HID 128
#define OUTF 64
#define NBMAX 400   // max buckets (N<=102400); N=100000 -> NB=391
#define BCAP 6144   // max edges staged in LDS per bucket (mean 4096, 30 sigma margin)

typedef __bf16 bf16x8 __attribute__((ext_vector_type(8)));
typedef __bf16 bf16x4 __attribute__((ext_vector_type(4)));
typedef float f32x4 __attribute__((ext_vector_type(4)));

// Feature tensors between layers are stored XCD-SLICED:
//   F_sl[slice][row][f]  with NSL=4 slices of 32 feats (64 B rows).
// slice = blockIdx&3 pins each slice to the XCD pair {s, s+4}.
// HARD LESSONS (measured):
//  - R3: GLOBAL node reorder breaks the sequential-window L2 contract
//    (FETCH 70->327 MB). Node processing order stays sequential.
//  - R4: f32 LDS atomicAdd = CAS retry loop on gfx950 -> 12.5x slower.
//  - R5: degree sorting (divergence fix) LOST (87.6->113, straggler tail
//    + scattered writes) -> divergence is not the agg limiter; the
//    request/address rate is. This version: 64 B full-line gathers (s=4),
//    csrc loaded once per group and shfl-distributed.

// Edge encoding after bucketing: pk = ((target & 255) << 24) | src
// (src < 2^24 since N <= 102400).

// ---- bucketing: LDS counting-sort by 256-node target bucket -------------

__global__ __launch_bounds__(256) void bucket_count(const int* __restrict__ ei, int E,
    int CH, int NB, int* __restrict__ gbk, int* __restrict__ bbase) {
  __shared__ int cnt[NBMAX];
  const int t = threadIdx.x, blk = blockIdx.x;
  for (int i = t; i < NB; i += 256) cnt[i] = 0;
  __syncthreads();
  int base = blk * CH, lim = min(base + CH, E);
  for (int i = base + t; i < lim; i += 256) atomicAdd(&cnt[ei[E + i] >> 8], 1);
  __syncthreads();
  for (int i = t; i < NB; i += 256) {
    int b = (i + blk) % NB;  // stagger to spread atomic line contention
    int v = cnt[b];
    bbase[(size_t)blk * NB + b] = (v > 0) ? atomicAdd(&gbk[b], v) : 0;
  }
}

__global__ __launch_bounds__(512) void bucket_scan(const int* __restrict__ gbk,
    int* __restrict__ gbkoff, int NB, int E) {
  __shared__ int ts[512];
  const int t = threadIdx.x;
  int v = (t < NB) ? gbk[t] : 0;
  ts[t] = v;
  __syncthreads();
  for (int off = 1; off < 512; off <<= 1) {
    int u = (t >= off) ? ts[t - off] : 0;
    __syncthreads();
    ts[t] += u;
    __syncthreads();
  }
  if (t < NB) gbkoff[t] = ts[t] - v;
  if (t == 0) gbkoff[NB] = E;
}

// scatter edges into bucket-grouped packed 4B array via LDS cursors
__global__ __launch_bounds__(256) void bucket_scatter(const int* __restrict__ ei, int E,
    int CH, int NB, const int* __restrict__ gbkoff, const int* __restrict__ bbase,
    unsigned int* __restrict__ pk) {
  __shared__ int cur[NBMAX];
  const int t = threadIdx.x, blk = blockIdx.x;
  for (int i = t; i < NB; i += 256)
    cur[i] = gbkoff[i] + bbase[(size_t)blk * NB + i];
  __syncthreads();
  int base = blk * CH, lim = min(base + CH, E);
  for (int i = base + t; i < lim; i += 256) {
    unsigned int s = (unsigned int)ei[i];
    int c = ei[E + i];
    int p = atomicAdd(&cur[c >> 8], 1);
    pk[p] = ((unsigned int)(c & 255) << 24) | s;
  }
}

// K4: per-bucket local CSR: ptr, dinv, target-sorted csrc (plain src ints).
__global__ __launch_bounds__(256) void bucket_csr(const unsigned int* __restrict__ pk,
    const int* __restrict__ gbkoff, int NB, int N, int E,
    float* __restrict__ dinv, int* __restrict__ ptr, int* __restrict__ csrc) {
  __shared__ unsigned int eb[BCAP];
  __shared__ int cnt[256], scn[256], cur[256];
  const int b = blockIdx.x, t = threadIdx.x;
  const int beg = gbkoff[b], end = gbkoff[b + 1];
  const int M = end - beg;
  cnt[t] = 0;
  __syncthreads();
  const bool inlds = (M <= BCAP);
  if (inlds) {
    for (int i = t; i < M; i += 256) {
      unsigned int r = pk[beg + i];
      eb[i] = r;
      atomicAdd(&cnt[r >> 24], 1);
    }
  } else {
    for (int i = t; i < M; i += 256) atomicAdd(&cnt[pk[beg + i] >> 24], 1);
  }
  __syncthreads();
  const int c0 = cnt[t];
  scn[t] = c0;
  __syncthreads();
  for (int off = 1; off < 256; off <<= 1) {
    int u = (t >= off) ? scn[t - off] : 0;
    __syncthreads();
    scn[t] += u;
    __syncthreads();
  }
  const int excl = scn[t] - c0;
  const int node = b * 256 + t;
  if (node < N) {
    ptr[node] = beg + excl;
    dinv[node] = rsqrtf((float)(c0 + 1));  // +1 self-loop
  }
  if (b == NB - 1 && t == 0) ptr[N] = E;
  cur[t] = excl;
  __syncthreads();
  if (inlds) {
    for (int i = t; i < M; i += 256) {
      unsigned int r = eb[i];
      int slot = atomicAdd(&cur[r >> 24], 1);
      csrc[beg + slot] = (int)(r & 0xFFFFFFu);
    }
  } else {
    for (int i = t; i < M; i += 256) {
      unsigned int r = pk[beg + i];
      int slot = atomicAdd(&cur[r >> 24], 1);
      csrc[beg + slot] = (int)(r & 0xFFFFFFu);
    }
  }
}

// ---- weight repack into MFMA B-fragment order ---------------------------

__global__ __launch_bounds__(256) void pack_all_kernel(const float* __restrict__ W1,
    const float* __restrict__ Wmu, const float* __restrict__ Wlv,
    __bf16* __restrict__ W1p, __bf16* __restrict__ Wcp) {
  int idx = blockIdx.x * 256 + threadIdx.x;  // 32768 + 16384 = 49152
  if (idx < 32768) {
    int j = idx & 7, l = (idx >> 3) & 63, t = (idx >> 9) & 7, s = idx >> 12;
    int k = s * 32 + (l >> 4) * 8 + j;
    int n = t * 16 + (l & 15);
    W1p[idx] = (__bf16)W1[k * HID + n];
  } else if (idx < 49152) {
    int i2 = idx - 32768;
    int j = i2 & 7, l = (i2 >> 3) & 63, t = (i2 >> 9) & 7, s = i2 >> 12;
    int k = s * 32 + (l >> 4) * 8 + j;
    int g = t * 16 + (l & 15);
    float v = (g < OUTF) ? Wmu[k * OUTF + g] : Wlv[k * OUTF + (g - OUTF)];
    Wcp[i2] = (__bf16)v;
  }
}

// ---- GEMM1 (MFMA, no LDS): Yb_sl = slice( dinv[row] * (X @ W1) ) --------

__global__ __launch_bounds__(256) void gemm1_mfma(const float* __restrict__ X,
    const __bf16* __restrict__ Wp, const float* __restrict__ dinv,
    __bf16* __restrict__ Yb, int nrows) {
  const int tid = threadIdx.x;
  const int lane = tid & 63;
  const int wave = tid >> 6;
  const int lm = lane & 15;
  const int q = lane >> 4;
  const int rowbase = blockIdx.x * 128 + wave * 32;

  const int r0 = min(rowbase + lm, nrows - 1);
  const int r1 = min(rowbase + 16 + lm, nrows - 1);
  const float* x0 = X + (size_t)r0 * N_FEATS_IN + q * 8;
  const float* x1 = X + (size_t)r1 * N_FEATS_IN + q * 8;

  const bf16x8* wp = (const bf16x8*)Wp;

  f32x4 acc[2][8];
#pragma unroll
  for (int m = 0; m < 2; ++m)
#pragma unroll
    for (int t = 0; t < 8; ++t) acc[m][t] = (f32x4)0.f;

#pragma unroll
  for (int s = 0; s < 8; ++s) {
    float4 l0 = *(const float4*)(x0 + s * 32);
    float4 h0 = *(const float4*)(x0 + s * 32 + 4);
    float4 l1 = *(const float4*)(x1 + s * 32);
    float4 h1 = *(const float4*)(x1 + s * 32 + 4);
    bf16x8 a0, a1;
    a0[0] = (__bf16)l0.x; a0[1] = (__bf16)l0.y; a0[2] = (__bf16)l0.z; a0[3] = (__bf16)l0.w;
    a0[4] = (__bf16)h0.x; a0[5] = (__bf16)h0.y; a0[6] = (__bf16)h0.z; a0[7] = (__bf16)h0.w;
    a1[0] = (__bf16)l1.x; a1[1] = (__bf16)l1.y; a1[2] = (__bf16)l1.z; a1[3] = (__bf16)l1.w;
    a1[4] = (__bf16)h1.x; a1[5] = (__bf16)h1.y; a1[6] = (__bf16)h1.z; a1[7] = (__bf16)h1.w;
#pragma unroll
    for (int t = 0; t < 8; ++t) {
      bf16x8 b = wp[(s * 8 + t) * 64 + lane];
      acc[0][t] = __builtin_amdgcn_mfma_f32_16x16x32_bf16(a0, b, acc[0][t], 0, 0, 0);
      acc[1][t] = __builtin_amdgcn_mfma_f32_16x16x32_bf16(a1, b, acc[1][t], 0, 0, 0);
    }
  }

  float dd[2][4];
#pragma unroll
  for (int m = 0; m < 2; ++m)
#pragma unroll
    for (int r2 = 0; r2 < 4; ++r2) {
      int row = rowbase + m * 16 + q * 4 + r2;
      dd[m][r2] = (row < nrows) ? dinv[row] : 0.f;
    }

  // sliced store: feat f = t*16+lm -> slice f>>5 = t>>1, offset (t&1)*16+lm
#pragma unroll
  for (int m = 0; m < 2; ++m) {
    int rb = rowbase + m * 16 + q * 4;
#pragma unroll
    for (int t = 0; t < 8; ++t) {
      __bf16* yslice = Yb + (size_t)(t >> 1) * nrows * 32;
      const int o = (t & 1) * 16 + lm;
#pragma unroll
      for (int r2 = 0; r2 < 4; ++r2) {
        int row = rb + r2;
        if (row < nrows)
          yslice[(size_t)row * 32 + o] = (__bf16)(acc[m][t][r2] * dd[m][r2]);
      }
    }
  }
}

// ---- aggregation, XCD-sliced (4 slices x 32 feats, 64 B rows) -----------
// slice = blockIdx & 3; sequential node order (L2 contract); 8 lanes per
// node (bf16x4 each), wave = 8 nodes. Per 8-edge batch: lane fl loads
// csrc[e+fl], all 8 shared via shfl -> 1 full-line gather per edge.
//   sum = F'[c] + sum_e F'[src_e]
//   relu: out = d*relu(d*sum + b)     plain: out = d*sum

__global__ __launch_bounds__(256) void agg_kernel(const __bf16* __restrict__ Fin,
    const int* __restrict__ ptr, const int* __restrict__ csrc,
    const float* __restrict__ dinv, const float* __restrict__ bias,
    __bf16* __restrict__ Fout, int do_relu, int N) {
  const int tid = threadIdx.x;
  const int s = blockIdx.x & 3;
  const int tb = blockIdx.x >> 2;
  const int g = tid >> 3;    // node slot within block (0..31)
  const int fl = tid & 7;    // 4 feats per lane within the 32-feat slice
  const int lane = tid & 63;
  const int c = tb * 32 + g;
  if (c >= N) return;

  const __bf16* F = Fin + (size_t)s * N * 32;
  const float d = dinv[c];
  bf16x4 sv = ((const bf16x4*)(F + (size_t)c * 32))[fl];  // self term
  float a0 = (float)sv[0], a1 = (float)sv[1], a2 = (float)sv[2], a3 = (float)sv[3];

  const int beg = ptr[c], end = ptr[c + 1];
  const int gbase = lane & 56;  // group base lane
  int e = beg;
  for (; e + 8 <= end; e += 8) {
    int rown = csrc[e + fl];   // one index per lane
    int r[8];
#pragma unroll
    for (int i = 0; i < 8; ++i) r[i] = __shfl(rown, gbase | i);
    bf16x4 v[8];
#pragma unroll
    for (int i = 0; i < 8; ++i) v[i] = ((const bf16x4*)(F + (size_t)r[i] * 32))[fl];
#pragma unroll
    for (int i = 0; i < 8; ++i) {
      a0 += (float)v[i][0];
      a1 += (float)v[i][1];
      a2 += (float)v[i][2];
      a3 += (float)v[i][3];
    }
  }
  for (; e < end; ++e) {
    int r = csrc[e];
    bf16x4 v = ((const bf16x4*)(F + (size_t)r * 32))[fl];
    a0 += (float)v[0];
    a1 += (float)v[1];
    a2 += (float)v[2];
    a3 += (float)v[3];
  }

  if (do_relu) {
    float4 bv = ((const float4*)bias)[s * 8 + fl];
    a0 = fmaxf(fmaf(d, a0, bv.x), 0.f) * d;
    a1 = fmaxf(fmaf(d, a1, bv.y), 0.f) * d;
    a2 = fmaxf(fmaf(d, a2, bv.z), 0.f) * d;
    a3 = fmaxf(fmaf(d, a3, bv.w), 0.f) * d;
  } else {
    a0 *= d; a1 *= d; a2 *= d; a3 *= d;
  }
  bf16x4 o;
  o[0] = (__bf16)a0; o[1] = (__bf16)a1; o[2] = (__bf16)a2; o[3] = (__bf16)a3;
  ((bf16x4*)(Fout + (size_t)s * N * 32 + (size_t)c * 32))[fl] = o;
}

// ---- GEMM2 (MFMA): [mu|lv] = G[N][128] @ Wc[128][128] + bias ------------
// A rows gathered from sliced layout: 16B chunk k (feats 8k..8k+8) lives at
// slice k>>2, row offset (k&3)*8.

__global__ __launch_bounds__(256) void gemm2_mfma(const __bf16* __restrict__ Gb,
    const __bf16* __restrict__ Wp, const float* __restrict__ bmu,
    const float* __restrict__ blv, float* __restrict__ out, int nrows, int ntiles) {
  __shared__ __bf16 bs[16384];  // 32 KB: full Wc in B-frag order
  const int tid = threadIdx.x;
  {
    const float4* s4 = (const float4*)Wp;
    float4* d4 = (float4*)bs;
#pragma unroll
    for (int i = 0; i < 8; ++i) d4[tid + 256 * i] = s4[tid + 256 * i];
  }
  __syncthreads();
  const int lane = tid & 63;
  const int wave = tid >> 6;
  const int lm = lane & 15;
  const int q = lane >> 4;
  const bf16x8* bsv = (const bf16x8*)bs;

  float bv[8];
  size_t obase[8];
#pragma unroll
  for (int t = 0; t < 8; ++t) {
    int col = t * 16 + lm;
    bv[t] = (col < OUTF) ? bmu[col] : blv[col - OUTF];
    obase[t] = (col < OUTF) ? (size_t)col : ((size_t)nrows * OUTF + (col - OUTF));
  }

  for (int tile = blockIdx.x; tile < ntiles; tile += gridDim.x) {
    const int row0 = tile * 64 + wave * 16;
    const int r = min(row0 + lm, nrows - 1);

    bf16x8 xa[4];
#pragma unroll
    for (int si = 0; si < 4; ++si) {
      int chunk = si * 4 + q;  // feats [8*chunk, 8*chunk+8)
      xa[si] = *(const bf16x8*)(Gb + (size_t)(chunk >> 2) * nrows * 32 +
                                (size_t)r * 32 + (chunk & 3) * 8);
    }

    f32x4 acc[8];
#pragma unroll
    for (int t = 0; t < 8; ++t) acc[t] = (f32x4)0.f;

#pragma unroll
    for (int si = 0; si < 4; ++si) {
#pragma unroll
      for (int t = 0; t < 8; ++t)
        acc[t] = __builtin_amdgcn_mfma_f32_16x16x32_bf16(xa[si], bsv[(si * 8 + t) * 64 + lane],
                                                         acc[t], 0, 0, 0);
    }
#pragma unroll
    for (int t = 0; t < 8; ++t) {
#pragma unroll
      for (int r2 = 0; r2 < 4; ++r2) {
        int row = row0 + q * 4 + r2;
        if (row < nrows) out[obase[t] + (size_t)row * OUTF] = acc[t][r2] + bv[t];
      }
    }
  }
}

// ---- launch -------------------------------------------------------------

extern "C" void kernel_launch(void* const* d_in, const int* in_sizes, int n_in,
                              void* d_out, int out_size, void* d_ws, size_t ws_size,
                              hipStream_t stream) {
  const float* X   = (const float*)d_in[0];
  const int*   ei  = (const int*)d_in[1];
  const float* W1  = (const float*)d_in[2];
  const float* b1  = (const float*)d_in[3];
  const float* Wmu = (const float*)d_in[4];
  const float* bmu = (const float*)d_in[5];
  const float* Wlv = (const float*)d_in[6];
  const float* blv = (const float*)d_in[7];
  float* out = (float*)d_out;

  const int N = in_sizes[0] / N_FEATS_IN;   // 100000
  const int E = in_sizes[1] / 2;            // 1600000

  char* ws = (char*)d_ws;
  size_t off = 0;
  auto alloc = [&](size_t bytes) -> void* {
    void* p = ws + off;
    off += (bytes + 255) & ~(size_t)255;
    return p;
  };
  __bf16* Yb   = (__bf16*)alloc((size_t)N * HID * 2);  // gemm1 out (sliced); reused as G
  __bf16* Hb   = (__bf16*)alloc((size_t)N * HID * 2);  // dinv*relu(Â Y + b1) (sliced)
  float* dinv  = (float*)alloc((size_t)N * 4);
  int*   ptr   = (int*)alloc((size_t)(N + 1) * 4);
  unsigned int* pk = (unsigned int*)alloc((size_t)E * 4);  // packed (tloc<<24)|src
  int*   csrc  = (int*)alloc((size_t)E * 4);
  int*   gbk   = (int*)alloc((size_t)NBMAX * 4);
  int*   gbkoff = (int*)alloc((size_t)(NBMAX + 1) * 4);
  int*   bbase = (int*)alloc((size_t)256 * NBMAX * 4);
  __bf16* W1p  = (__bf16*)alloc(32768 * 2);
  __bf16* Wcp  = (__bf16*)alloc(16384 * 2);
  (void)ws_size; (void)n_in; (void)out_size;

  const int NB = (N + 255) >> 8;            // 391
  const int P = 256;
  const int CH = (E + P - 1) / P;           // 6250

  hipMemsetAsync(gbk, 0, (size_t)NB * 4, stream);
  bucket_count<<<P, 256, 0, stream>>>(ei, E, CH, NB, gbk, bbase);
  bucket_scan<<<1, 512, 0, stream>>>(gbk, gbkoff, NB, E);
  bucket_scatter<<<P, 256, 0, stream>>>(ei, E, CH, NB, gbkoff, bbase, pk);
  bucket_csr<<<NB, 256, 0, stream>>>(pk, gbkoff, NB, N, E, dinv, ptr, csrc);
  pack_all_kernel<<<192, 256, 0, stream>>>(W1, Wmu, Wlv, W1p, Wcp);

  int g1 = (N + 127) / 128;
  gemm1_mfma<<<g1, 256, 0, stream>>>(X, W1p, dinv, Yb, N);
  int ga = ((N + 31) / 32) * 4;  // 4 slices x 32-node blocks
  agg_kernel<<<ga, 256, 0, stream>>>(Yb, ptr, csrc, dinv, b1, Hb, 1, N);  // H'
  agg_kernel<<<ga, 256, 0, stream>>>(Hb, ptr, csrc, dinv, b1, Yb, 0, N);  // G
  int ntiles2 = (N + 63) / 64;
  int g2 = ntiles2 < 768 ? ntiles2 : 768;
  gemm2_mfma<<<g2, 256, 0, stream>>>(Yb, Wcp, bmu, blv, out, N, ntiles2);
}

// Round 7
// 419.251 us; speedup vs baseline: 5.8465x; 1.0259x over previous
//
#include <hip/hip_runtime.h>
#include <hip/hip_bf16.h>
#include <cstdint>

#define N_FEATS_IN 256
#define HID 128
#define OUTF 64
#define NBMAX 400   // max buckets (N<=102400); N=100000 -> NB=391
#define BCAP 6144   // max edges staged in LDS per bucket (mean 4096, 30 sigma margin)

typedef __bf16 bf16x8 __attribute__((ext_vector_type(8)));
typedef __bf16 bf16x4 __attribute__((ext_vector_type(4)));
typedef float f32x4 __attribute__((ext_vector_type(4)));

// Feature tensors between layers are stored XCD-SLICED:
//   F_sl[slice][row][f]  with NSL=4 slices of 32 feats (64 B rows).
// slice = blockIdx&3 pins each slice to the XCD pair {s, s+4}.
// HARD LESSONS (measured):
//  - R3: GLOBAL node reorder breaks the sequential-window L2 contract
//    (FETCH 70->327 MB). Node processing order stays sequential.
//  - R4: f32 LDS atomicAdd = CAS retry loop on gfx950 -> 12.5x slower.
//  - R5: degree sorting LOST (straggler tail) -> agg limiter is the
//    request/address rate, fixed in R6 by 64 B full-line gathers (s=4).
//  - R6: gemm1 (no-LDS) was grid-limited: 782 blocks = 38% static
//    occupancy -> latency-bound at MfmaUtil 3%. This version: 16 rows
//    per wave, 64 per block, 1563 blocks (76% static) + 1-deep X prefetch.

// ---- bucketing: LDS counting-sort by 256-node target bucket -------------

__global__ __launch_bounds__(256) void bucket_count(const int* __restrict__ ei, int E,
    int CH, int NB, int* __restrict__ gbk, int* __restrict__ bbase) {
  __shared__ int cnt[NBMAX];
  const int t = threadIdx.x, blk = blockIdx.x;
  for (int i = t; i < NB; i += 256) cnt[i] = 0;
  __syncthreads();
  int base = blk * CH, lim = min(base + CH, E);
  for (int i = base + t; i < lim; i += 256) atomicAdd(&cnt[ei[E + i] >> 8], 1);
  __syncthreads();
  for (int i = t; i < NB; i += 256) {
    int b = (i + blk) % NB;  // stagger to spread atomic line contention
    int v = cnt[b];
    bbase[(size_t)blk * NB + b] = (v > 0) ? atomicAdd(&gbk[b], v) : 0;
  }
}

__global__ __launch_bounds__(512) void bucket_scan(const int* __restrict__ gbk,
    int* __restrict__ gbkoff, int NB, int E) {
  __shared__ int ts[512];
  const int t = threadIdx.x;
  int v = (t < NB) ? gbk[t] : 0;
  ts[t] = v;
  __syncthreads();
  for (int off = 1; off < 512; off <<= 1) {
    int u = (t >= off) ? ts[t - off] : 0;
    __syncthreads();
    ts[t] += u;
    __syncthreads();
  }
  if (t < NB) gbkoff[t] = ts[t] - v;
  if (t == 0) gbkoff[NB] = E;
}

// scatter edges into bucket-grouped packed 4B array via LDS cursors
__global__ __launch_bounds__(256) void bucket_scatter(const int* __restrict__ ei, int E,
    int CH, int NB, const int* __restrict__ gbkoff, const int* __restrict__ bbase,
    unsigned int* __restrict__ pk) {
  __shared__ int cur[NBMAX];
  const int t = threadIdx.x, blk = blockIdx.x;
  for (int i = t; i < NB; i += 256)
    cur[i] = gbkoff[i] + bbase[(size_t)blk * NB + i];
  __syncthreads();
  int base = blk * CH, lim = min(base + CH, E);
  for (int i = base + t; i < lim; i += 256) {
    unsigned int s = (unsigned int)ei[i];
    int c = ei[E + i];
    int p = atomicAdd(&cur[c >> 8], 1);
    pk[p] = ((unsigned int)(c & 255) << 24) | s;
  }
}

// K4: per-bucket local CSR: ptr, dinv, target-sorted csrc (plain src ints).
__global__ __launch_bounds__(256) void bucket_csr(const unsigned int* __restrict__ pk,
    const int* __restrict__ gbkoff, int NB, int N, int E,
    float* __restrict__ dinv, int* __restrict__ ptr, int* __restrict__ csrc) {
  __shared__ unsigned int eb[BCAP];
  __shared__ int cnt[256], scn[256], cur[256];
  const int b = blockIdx.x, t = threadIdx.x;
  const int beg = gbkoff[b], end = gbkoff[b + 1];
  const int M = end - beg;
  cnt[t] = 0;
  __syncthreads();
  const bool inlds = (M <= BCAP);
  if (inlds) {
    for (int i = t; i < M; i += 256) {
      unsigned int r = pk[beg + i];
      eb[i] = r;
      atomicAdd(&cnt[r >> 24], 1);
    }
  } else {
    for (int i = t; i < M; i += 256) atomicAdd(&cnt[pk[beg + i] >> 24], 1);
  }
  __syncthreads();
  const int c0 = cnt[t];
  scn[t] = c0;
  __syncthreads();
  for (int off = 1; off < 256; off <<= 1) {
    int u = (t >= off) ? scn[t - off] : 0;
    __syncthreads();
    scn[t] += u;
    __syncthreads();
  }
  const int excl = scn[t] - c0;
  const int node = b * 256 + t;
  if (node < N) {
    ptr[node] = beg + excl;
    dinv[node] = rsqrtf((float)(c0 + 1));  // +1 self-loop
  }
  if (b == NB - 1 && t == 0) ptr[N] = E;
  cur[t] = excl;
  __syncthreads();
  if (inlds) {
    for (int i = t; i < M; i += 256) {
      unsigned int r = eb[i];
      int slot = atomicAdd(&cur[r >> 24], 1);
      csrc[beg + slot] = (int)(r & 0xFFFFFFu);
    }
  } else {
    for (int i = t; i < M; i += 256) {
      unsigned int r = pk[beg + i];
      int slot = atomicAdd(&cur[r >> 24], 1);
      csrc[beg + slot] = (int)(r & 0xFFFFFFu);
    }
  }
}

// ---- weight repack into MFMA B-fragment order ---------------------------

__global__ __launch_bounds__(256) void pack_all_kernel(const float* __restrict__ W1,
    const float* __restrict__ Wmu, const float* __restrict__ Wlv,
    __bf16* __restrict__ W1p, __bf16* __restrict__ Wcp) {
  int idx = blockIdx.x * 256 + threadIdx.x;  // 32768 + 16384 = 49152
  if (idx < 32768) {
    int j = idx & 7, l = (idx >> 3) & 63, t = (idx >> 9) & 7, s = idx >> 12;
    int k = s * 32 + (l >> 4) * 8 + j;
    int n = t * 16 + (l & 15);
    W1p[idx] = (__bf16)W1[k * HID + n];
  } else if (idx < 49152) {
    int i2 = idx - 32768;
    int j = i2 & 7, l = (i2 >> 3) & 63, t = (i2 >> 9) & 7, s = i2 >> 12;
    int k = s * 32 + (l >> 4) * 8 + j;
    int g = t * 16 + (l & 15);
    float v = (g < OUTF) ? Wmu[k * OUTF + g] : Wlv[k * OUTF + (g - OUTF)];
    Wcp[i2] = (__bf16)v;
  }
}

// ---- GEMM1 (MFMA, no LDS): Yb_sl = slice( dinv[row] * (X @ W1) ) --------
// 16 rows per wave, 64 per block -> 1563 blocks (76% static occupancy);
// 1-deep X prefetch hides the global-load latency under the 8 MFMAs.

__global__ __launch_bounds__(256) void gemm1_mfma(const float* __restrict__ X,
    const __bf16* __restrict__ Wp, const float* __restrict__ dinv,
    __bf16* __restrict__ Yb, int nrows) {
  const int tid = threadIdx.x;
  const int lane = tid & 63;
  const int wave = tid >> 6;
  const int lm = lane & 15;
  const int q = lane >> 4;
  const int rowbase = blockIdx.x * 64 + wave * 16;

  const int r0 = min(rowbase + lm, nrows - 1);
  const float* x0 = X + (size_t)r0 * N_FEATS_IN + q * 8;

  const bf16x8* wp = (const bf16x8*)Wp;

  f32x4 acc[8];
#pragma unroll
  for (int t = 0; t < 8; ++t) acc[t] = (f32x4)0.f;

  float4 l0 = *(const float4*)(x0);
  float4 h0 = *(const float4*)(x0 + 4);

#pragma unroll
  for (int s = 0; s < 8; ++s) {
    bf16x8 a0;
    a0[0] = (__bf16)l0.x; a0[1] = (__bf16)l0.y; a0[2] = (__bf16)l0.z; a0[3] = (__bf16)l0.w;
    a0[4] = (__bf16)h0.x; a0[5] = (__bf16)h0.y; a0[6] = (__bf16)h0.z; a0[7] = (__bf16)h0.w;
    if (s < 7) {  // prefetch next k-step while MFMAs run
      l0 = *(const float4*)(x0 + (s + 1) * 32);
      h0 = *(const float4*)(x0 + (s + 1) * 32 + 4);
    }
#pragma unroll
    for (int t = 0; t < 8; ++t) {
      bf16x8 b = wp[(s * 8 + t) * 64 + lane];
      acc[t] = __builtin_amdgcn_mfma_f32_16x16x32_bf16(a0, b, acc[t], 0, 0, 0);
    }
  }

  float dd[4];
#pragma unroll
  for (int r2 = 0; r2 < 4; ++r2) {
    int row = rowbase + q * 4 + r2;
    dd[r2] = (row < nrows) ? dinv[row] : 0.f;
  }

  // sliced store: feat f = t*16+lm -> slice f>>5 = t>>1, offset (t&1)*16+lm
  const int rb = rowbase + q * 4;
#pragma unroll
  for (int t = 0; t < 8; ++t) {
    __bf16* yslice = Yb + (size_t)(t >> 1) * nrows * 32;
    const int o = (t & 1) * 16 + lm;
#pragma unroll
    for (int r2 = 0; r2 < 4; ++r2) {
      int row = rb + r2;
      if (row < nrows)
        yslice[(size_t)row * 32 + o] = (__bf16)(acc[t][r2] * dd[r2]);
    }
  }
}

// ---- aggregation, XCD-sliced (4 slices x 32 feats, 64 B rows) -----------
// slice = blockIdx & 3; sequential node order (L2 contract); 8 lanes per
// node (bf16x4 each), wave = 8 nodes. Per 8-edge batch: lane fl loads
// csrc[e+fl], all 8 shared via shfl -> 1 full-line gather per edge.
//   sum = F'[c] + sum_e F'[src_e]
//   relu: out = d*relu(d*sum + b)     plain: out = d*sum

__global__ __launch_bounds__(256) void agg_kernel(const __bf16* __restrict__ Fin,
    const int* __restrict__ ptr, const int* __restrict__ csrc,
    const float* __restrict__ dinv, const float* __restrict__ bias,
    __bf16* __restrict__ Fout, int do_relu, int N) {
  const int tid = threadIdx.x;
  const int s = blockIdx.x & 3;
  const int tb = blockIdx.x >> 2;
  const int g = tid >> 3;    // node slot within block (0..31)
  const int fl = tid & 7;    // 4 feats per lane within the 32-feat slice
  const int lane = tid & 63;
  const int c = tb * 32 + g;
  if (c >= N) return;

  const __bf16* F = Fin + (size_t)s * N * 32;
  const float d = dinv[c];
  bf16x4 sv = ((const bf16x4*)(F + (size_t)c * 32))[fl];  // self term
  float a0 = (float)sv[0], a1 = (float)sv[1], a2 = (float)sv[2], a3 = (float)sv[3];

  const int beg = ptr[c], end = ptr[c + 1];
  const int gbase = lane & 56;  // group base lane
  int e = beg;
  for (; e + 8 <= end; e += 8) {
    int rown = csrc[e + fl];   // one index per lane
    int r[8];
#pragma unroll
    for (int i = 0; i < 8; ++i) r[i] = __shfl(rown, gbase | i);
    bf16x4 v[8];
#pragma unroll
    for (int i = 0; i < 8; ++i) v[i] = ((const bf16x4*)(F + (size_t)r[i] * 32))[fl];
#pragma unroll
    for (int i = 0; i < 8; ++i) {
      a0 += (float)v[i][0];
      a1 += (float)v[i][1];
      a2 += (float)v[i][2];
      a3 += (float)v[i][3];
    }
  }
  for (; e < end; ++e) {
    int r = csrc[e];
    bf16x4 v = ((const bf16x4*)(F + (size_t)r * 32))[fl];
    a0 += (float)v[0];
    a1 += (float)v[1];
    a2 += (float)v[2];
    a3 += (float)v[3];
  }

  if (do_relu) {
    float4 bv = ((const float4*)bias)[s * 8 + fl];
    a0 = fmaxf(fmaf(d, a0, bv.x), 0.f) * d;
    a1 = fmaxf(fmaf(d, a1, bv.y), 0.f) * d;
    a2 = fmaxf(fmaf(d, a2, bv.z), 0.f) * d;
    a3 = fmaxf(fmaf(d, a3, bv.w), 0.f) * d;
  } else {
    a0 *= d; a1 *= d; a2 *= d; a3 *= d;
  }
  bf16x4 o;
  o[0] = (__bf16)a0; o[1] = (__bf16)a1; o[2] = (__bf16)a2; o[3] = (__bf16)a3;
  ((bf16x4*)(Fout + (size_t)s * N * 32 + (size_t)c * 32))[fl] = o;
}

// ---- GEMM2 (MFMA): [mu|lv] = G[N][128] @ Wc[128][128] + bias ------------
// A rows gathered from sliced layout: 16B chunk k (feats 8k..8k+8) lives at
// slice k>>2, row offset (k&3)*8.

__global__ __launch_bounds__(256) void gemm2_mfma(const __bf16* __restrict__ Gb,
    const __bf16* __restrict__ Wp, const float* __restrict__ bmu,
    const float* __restrict__ blv, float* __restrict__ out, int nrows, int ntiles) {
  __shared__ __bf16 bs[16384];  // 32 KB: full Wc in B-frag order
  const int tid = threadIdx.x;
  {
    const float4* s4 = (const float4*)Wp;
    float4* d4 = (float4*)bs;
#pragma unroll
    for (int i = 0; i < 8; ++i) d4[tid + 256 * i] = s4[tid + 256 * i];
  }
  __syncthreads();
  const int lane = tid & 63;
  const int wave = tid >> 6;
  const int lm = lane & 15;
  const int q = lane >> 4;
  const bf16x8* bsv = (const bf16x8*)bs;

  float bv[8];
  size_t obase[8];
#pragma unroll
  for (int t = 0; t < 8; ++t) {
    int col = t * 16 + lm;
    bv[t] = (col < OUTF) ? bmu[col] : blv[col - OUTF];
    obase[t] = (col < OUTF) ? (size_t)col : ((size_t)nrows * OUTF + (col - OUTF));
  }

  for (int tile = blockIdx.x; tile < ntiles; tile += gridDim.x) {
    const int row0 = tile * 64 + wave * 16;
    const int r = min(row0 + lm, nrows - 1);

    bf16x8 xa[4];
#pragma unroll
    for (int si = 0; si < 4; ++si) {
      int chunk = si * 4 + q;  // feats [8*chunk, 8*chunk+8)
      xa[si] = *(const bf16x8*)(Gb + (size_t)(chunk >> 2) * nrows * 32 +
                                (size_t)r * 32 + (chunk & 3) * 8);
    }

    f32x4 acc[8];
#pragma unroll
    for (int t = 0; t < 8; ++t) acc[t] = (f32x4)0.f;

#pragma unroll
    for (int si = 0; si < 4; ++si) {
#pragma unroll
      for (int t = 0; t < 8; ++t)
        acc[t] = __builtin_amdgcn_mfma_f32_16x16x32_bf16(xa[si], bsv[(si * 8 + t) * 64 + lane],
                                                         acc[t], 0, 0, 0);
    }
#pragma unroll
    for (int t = 0; t < 8; ++t) {
#pragma unroll
      for (int r2 = 0; r2 < 4; ++r2) {
        int row = row0 + q * 4 + r2;
        if (row < nrows) out[obase[t] + (size_t)row * OUTF] = acc[t][r2] + bv[t];
      }
    }
  }
}

// ---- launch -------------------------------------------------------------

extern "C" void kernel_launch(void* const* d_in, const int* in_sizes, int n_in,
                              void* d_out, int out_size, void* d_ws, size_t ws_size,
                              hipStream_t stream) {
  const float* X   = (const float*)d_in[0];
  const int*   ei  = (const int*)d_in[1];
  const float* W1  = (const float*)d_in[2];
  const float* b1  = (const float*)d_in[3];
  const float* Wmu = (const float*)d_in[4];
  const float* bmu = (const float*)d_in[5];
  const float* Wlv = (const float*)d_in[6];
  const float* blv = (const float*)d_in[7];
  float* out = (float*)d_out;

  const int N = in_sizes[0] / N_FEATS_IN;   // 100000
  const int E = in_sizes[1] / 2;            // 1600000

  char* ws = (char*)d_ws;
  size_t off = 0;
  auto alloc = [&](size_t bytes) -> void* {
    void* p = ws + off;
    off += (bytes + 255) & ~(size_t)255;
    return p;
  };
  __bf16* Yb   = (__bf16*)alloc((size_t)N * HID * 2);  // gemm1 out (sliced); reused as G
  __bf16* Hb   = (__bf16*)alloc((size_t)N * HID * 2);  // dinv*relu(Â Y + b1) (sliced)
  float* dinv  = (float*)alloc((size_t)N * 4);
  int*   ptr   = (int*)alloc((size_t)(N + 1) * 4);
  unsigned int* pk = (unsigned int*)alloc((size_t)E * 4);  // packed (tloc<<24)|src
  int*   csrc  = (int*)alloc((size_t)E * 4);
  int*   gbk   = (int*)alloc((size_t)NBMAX * 4);
  int*   gbkoff = (int*)alloc((size_t)(NBMAX + 1) * 4);
  int*   bbase = (int*)alloc((size_t)256 * NBMAX * 4);
  __bf16* W1p  = (__bf16*)alloc(32768 * 2);
  __bf16* Wcp  = (__bf16*)alloc(16384 * 2);
  (void)ws_size; (void)n_in; (void)out_size;

  const int NB = (N + 255) >> 8;            // 391
  const int P = 256;
  const int CH = (E + P - 1) / P;           // 6250

  hipMemsetAsync(gbk, 0, (size_t)NB * 4, stream);
  bucket_count<<<P, 256, 0, stream>>>(ei, E, CH, NB, gbk, bbase);
  bucket_scan<<<1, 512, 0, stream>>>(gbk, gbkoff, NB, E);
  bucket_scatter<<<P, 256, 0, stream>>>(ei, E, CH, NB, gbkoff, bbase, pk);
  bucket_csr<<<NB, 256, 0, stream>>>(pk, gbkoff, NB, N, E, dinv, ptr, csrc);
  pack_all_kernel<<<192, 256, 0, stream>>>(W1, Wmu, Wlv, W1p, Wcp);

  int g1 = (N + 63) / 64;
  gemm1_mfma<<<g1, 256, 0, stream>>>(X, W1p, dinv, Yb, N);
  int ga = ((N + 31) / 32) * 4;  // 4 slices x 32-node blocks
  agg_kernel<<<ga, 256, 0, stream>>>(Yb, ptr, csrc, dinv, b1, Hb, 1, N);  // H'
  agg_kernel<<<ga, 256, 0, stream>>>(Hb, ptr, csrc, dinv, b1, Yb, 0, N);  // G
  int ntiles2 = (N + 63) / 64;
  int g2 = ntiles2 < 768 ? ntiles2 : 768;
  gemm2_mfma<<<g2, 256, 0, stream>>>(Yb, Wcp, bmu, blv, out, N, ntiles2);
}